// Round 7
// baseline (485.091 us; speedup 1.0000x reference)
//
#include <hip/hip_runtime.h>
#include <math.h>

#define T_TOK 16384
#define M_MSG 256
#define L_TOK 64
#define KK 6
#define NQ (M_MSG * KK)   // 1536
#define D_HID 256
#define NH 4
#define HD 64
#define KT 10
#define NBATCH 8

// raw barrier: ds visibility only (lgkmcnt); vmcnt prefetch stays in flight
#define BAR() do {                                        \
    asm volatile("s_waitcnt lgkmcnt(0)" ::: "memory");    \
    __builtin_amdgcn_s_barrier();                         \
    asm volatile("" ::: "memory");                        \
  } while (0)

// ---------- helpers ----------
__device__ __forceinline__ unsigned ordf(float f) {
  unsigned u = __float_as_uint(f);
  return (u & 0x80000000u) ? ~u : (u | 0x80000000u);
}
__device__ __forceinline__ float unordf(unsigned u) {
  return __uint_as_float((u & 0x80000000u) ? (u ^ 0x80000000u) : ~u);
}

// ---------- 0. weight k-panel transpose ----------
__global__ __launch_bounds__(64) void wpanel_kernel(
    const float* __restrict__ Wk, const float* __restrict__ Wv,
    const float* __restrict__ Wq, const float* __restrict__ Wo,
    const float* __restrict__ Wi1, float4* __restrict__ WkP,
    float4* __restrict__ WvP, float4* __restrict__ WqP,
    float4* __restrict__ WoP, float4* __restrict__ Wi1P) {
  int c = blockIdx.x;    // 0..255 (column)
  int k4 = threadIdx.x;  // 0..63 (dim group)
  WkP[k4 * 256 + c] = ((const float4*)(Wk + (size_t)c * 256))[k4];
  WvP[k4 * 256 + c] = ((const float4*)(Wv + (size_t)c * 256))[k4];
  WqP[k4 * 256 + c] = ((const float4*)(Wq + (size_t)c * 256))[k4];
  WoP[k4 * 256 + c] = ((const float4*)(Wo + (size_t)c * 256))[k4];
  if (c < 128) Wi1P[k4 * 128 + c] = ((const float4*)(Wi1 + (size_t)c * 256))[k4];
}

// ---------- 1. importance MLP ----------
__global__ __launch_bounds__(128) void imp_kernel(
    const float* __restrict__ X, const float4* __restrict__ Wi1P,
    const float* __restrict__ bi1, const float* __restrict__ Wi2,
    const float* __restrict__ bi2, float* __restrict__ imp) {
  __shared__ float xs[16][256];
  __shared__ float partial[2][16];
  int t0 = blockIdx.x * 16;
  int tid = threadIdx.x;  // 0..127, = hidden index j
  const float4* Xv = (const float4*)(X + (size_t)t0 * 256);
  float4* xsv = (float4*)&xs[0][0];
  for (int r = tid; r < 1024; r += 128) xsv[r] = Xv[r];
  __syncthreads();
  float acc[16];
#pragma unroll
  for (int tt = 0; tt < 16; ++tt) acc[tt] = 0.f;
  for (int i4 = 0; i4 < 64; ++i4) {
    float4 w = Wi1P[i4 * 128 + tid];  // coalesced panel load
#pragma unroll
    for (int tt = 0; tt < 16; ++tt) {
      float4 x = ((const float4*)xs[tt])[i4];
      acc[tt] += x.x * w.x + x.y * w.y + x.z * w.z + x.w * w.w;
    }
  }
  float b1 = bi1[tid], w2 = Wi2[tid];
  float p[16];
#pragma unroll
  for (int tt = 0; tt < 16; ++tt) {
    float hh = acc[tt] + b1;
    hh = hh > 0.f ? hh : 0.f;
    p[tt] = hh * w2;
  }
#pragma unroll
  for (int s = 1; s < 64; s <<= 1) {
#pragma unroll
    for (int tt = 0; tt < 16; ++tt) p[tt] += __shfl_xor(p[tt], s, 64);
  }
  int lane = tid & 63, w = tid >> 6;
  if (lane == 0) {
#pragma unroll
    for (int tt = 0; tt < 16; ++tt) partial[w][tt] = p[tt];
  }
  __syncthreads();
  if (tid < 16) imp[t0 + tid] = partial[0][tid] + partial[1][tid] + bi2[0];
}

// ---------- 2. per-message top-6 + (block M_MSG) batch ranges ----------
__global__ __launch_bounds__(64) void topsel_kernel(
    const float* __restrict__ imp, const int* __restrict__ mb,
    const int* __restrict__ bidx, int* __restrict__ selected,
    int* __restrict__ lo, int* __restrict__ hi) {
  int m = blockIdx.x;
  if (m == M_MSG) {  // fused ranges computation
    int g = threadIdx.x;
    if (g < NBATCH) {
      int l = 0;
      while (l < M_MSG && bidx[l] < g) ++l;
      int h = l;
      while (h < M_MSG && bidx[h] == g) ++h;
      lo[g] = l * L_TOK;
      hi[g] = h * L_TOK;
    }
    return;
  }
  int l = threadIdx.x;  // 0..63
  float myv = imp[m * 64 + l];
  int start = mb[2 * m];
  for (int k = 0; k < KK; ++k) {
    float rv = myv;
    int ri = l;
#pragma unroll
    for (int s = 1; s < 64; s <<= 1) {
      float ov = __shfl_xor(rv, s, 64);
      int oi = __shfl_xor(ri, s, 64);
      if (ov > rv || (ov == rv && oi < ri)) { rv = ov; ri = oi; }
    }
    if (l == 0) selected[m * KK + k] = start + ri;
    if (l == ri) myv = -INFINITY;
  }
}

// ---------- 4. fused K+V+Q projections (panel weights) ----------
__global__ __launch_bounds__(256) void projkvq_kernel(
    const float* __restrict__ X, const float4* __restrict__ WkP,
    const float* __restrict__ bk, const float4* __restrict__ WvP,
    const float* __restrict__ bv, const float4* __restrict__ WqP,
    const float* __restrict__ bq, const int* __restrict__ selected,
    float* __restrict__ Kout, float* __restrict__ Vout,
    float* __restrict__ Qout) {
  __shared__ float xs[32][260];  // +4 pad: transpose reads 2-way max
  int tid = threadIdx.x;
  if (blockIdx.x < T_TOK / 16) {
    // ---- KV path ----
    int r0 = blockIdx.x * 16;
    const float4* Xv = (const float4*)(X + (size_t)r0 * 256);
    for (int n = tid; n < 1024; n += 256) {
      int row = n >> 6, sl = n & 63;
      ((float4*)xs[row])[sl] = Xv[row * 64 + sl];
    }
    __syncthreads();
    float ak[16], av[16];
#pragma unroll
    for (int tt = 0; tt < 16; ++tt) { ak[tt] = 0.f; av[tt] = 0.f; }
    for (int i4 = 0; i4 < 64; ++i4) {
      float4 wk = WkP[i4 * 256 + tid];  // coalesced panel loads
      float4 wv = WvP[i4 * 256 + tid];
#pragma unroll
      for (int tt = 0; tt < 16; ++tt) {
        float4 x = ((const float4*)xs[tt])[i4];
        ak[tt] += x.x * wk.x + x.y * wk.y + x.z * wk.z + x.w * wk.w;
        av[tt] += x.x * wv.x + x.y * wv.y + x.z * wv.z + x.w * wv.w;
      }
    }
    float bkj = bk[tid], bvj = bv[tid];
#pragma unroll 1
    for (int tt = 0; tt < 16; ++tt)
      Vout[(size_t)(r0 + tt) * 256 + tid] = av[tt] + bvj;
    __syncthreads();  // all FMA reads of xs done
#pragma unroll
    for (int tt = 0; tt < 16; ++tt) xs[tt][tid] = ak[tt] + bkj;
    __syncthreads();
    float4* K4v = (float4*)Kout;
#pragma unroll
    for (int i = 0; i < 4; ++i) {
      int idx = i * 256 + tid;
      int hd4 = idx >> 4, r = idx & 15;
      float4 kv = *(const float4*)&xs[r][hd4 * 4];
      K4v[(size_t)hd4 * T_TOK + r0 + r] = kv;
    }
  } else {
    // ---- Q path (gathered rows, scaled) ----
    int r0 = (blockIdx.x - T_TOK / 16) * 32;
    for (int rr = 0; rr < 32; ++rr) {
      int r = r0 + rr;
      if (r < NQ) xs[rr][tid] = X[(size_t)selected[r] * 256 + tid];
    }
    __syncthreads();
    float acc[32];
#pragma unroll
    for (int tt = 0; tt < 32; ++tt) acc[tt] = 0.f;
    for (int i4 = 0; i4 < 64; ++i4) {
      float4 w = WqP[i4 * 256 + tid];
#pragma unroll
      for (int tt = 0; tt < 32; ++tt) {
        float4 x = ((const float4*)xs[tt])[i4];
        acc[tt] += x.x * w.x + x.y * w.y + x.z * w.z + x.w * w.w;
      }
    }
    float bj = bq[tid];
#pragma unroll 1
    for (int tt = 0; tt < 32; ++tt) {
      int r = r0 + tt;
      if (r < NQ) Qout[(size_t)r * 256 + tid] = (acc[tt] + bj) * 0.125f;
    }
  }
}

// ---------- 5. scores + per-split top-10 ----------
// block = (message-pair, h, split): 1024 blocks, 256 threads = 4 waves.
// The 4 waves SHARE each 64-key chunk through LDS (kbuf dbuf 2x16KB):
// each wave stages 4 dim-rows (coalesced 64x16B global load -> reg ->
// ds_write), so each K line is fetched from L2 once per BLOCK (4x fewer
// line-requests than one-wave-per-stream). lgkmcnt-only BAR() keeps the
// next chunk's global loads in flight across barriers; they land during
// the next compute. bidx sorted => pair's key range is the contiguous
// union [lo(g0), hi(g1)); each wave masks validity by its own message's
// batch range. Wave w owns 3 queries (r5's register top-10 lists, best
// measured); per-lane u64 lists + shfl extraction-merge epilogue.
__global__ __launch_bounds__(256) void scores_kernel(
    const float* __restrict__ Q, const float* __restrict__ K4,
    const int* __restrict__ lo_, const int* __restrict__ hi_,
    const int* __restrict__ bidx, unsigned long long* __restrict__ topk2) {
  int bid = blockIdx.x;
  // XCD swizzle: 1024 blocks -> contiguous 128-block slab per XCD.
  int sw = (bid & 7) * (M_MSG / 2 * NH * 2 / 8) + (bid >> 3);
  int pr = sw >> 3;        // message pair 0..127
  int h = (sw >> 1) & 3;
  int sp = sw & 1;
  int tid = threadIdx.x, lane = tid & 63, w = tid >> 6;
  int m0 = pr * 2;
  int mw = m0 + (w >> 1);           // this wave's message
  int gw = bidx[mw];
  int myLo = lo_[gw], myHi = hi_[gw];
  int loU = lo_[bidx[m0]];
  int hiU = hi_[bidx[m0 + 1]];
  int range = hiU - loU;
  int n_all = (range + 63) >> 6;
  int n0 = (n_all + 1) >> 1;
  int nt = sp ? (n_all - n0) : n0;
  int start = loU + (sp ? n0 * 64 : 0);

  __shared__ float4 qs4[12][16];        // 12 queries x 64 dims (3 KB)
  __shared__ float4 kbuf[2][16][64];    // dbuf: 16 d4-rows x 64 keys (32 KB)

  const float4* Qv = (const float4*)Q;
  const float4* Kh = (const float4*)K4 + (size_t)h * 16 * T_TOK;

  float4 pre[4];
  auto issue = [&](int t) {  // coalesced: 64 lanes x 16B contiguous per row
    int tc = start + t * 64 + lane;
    if (tc >= hiU) tc = hiU - 1;
#pragma unroll
    for (int i = 0; i < 4; ++i)
      pre[i] = Kh[(size_t)(w * 4 + i) * T_TOK + tc];
  };
  auto writeb = [&](int nb) {
#pragma unroll
    for (int i = 0; i < 4; ++i) kbuf[nb][w * 4 + i][lane] = pre[i];
  };

  issue(0);
  if (tid < 192) {
    int qq = tid >> 4, d4 = tid & 15;
    qs4[qq][d4] = Qv[(size_t)(pr * 12 + qq) * 64 + h * 16 + d4];
  }
  BAR();
  writeb(0);
  if (nt > 1) issue(1);
  BAR();

  unsigned long long lst[3][KT];
#pragma unroll
  for (int j = 0; j < 3; ++j)
#pragma unroll
    for (int k = 0; k < KT; ++k) lst[j][k] = 0ULL;

  float acc[3];
#pragma unroll 1
  for (int t = 0; t < nt; ++t) {
    acc[0] = 0.f; acc[1] = 0.f; acc[2] = 0.f;
    const float4(*kb)[64] = kbuf[t & 1];
#pragma unroll
    for (int d4 = 0; d4 < 16; ++d4) {
      float4 kv = kb[d4][lane];
#pragma unroll
      for (int j = 0; j < 3; ++j) {
        float4 q = qs4[w * 3 + j][d4];
        acc[j] += kv.x * q.x + kv.y * q.y + kv.z * q.z + kv.w * q.w;
      }
    }
    // ---- validity + per-lane register top-10 insert (r5 scheme) ----
    int tkn = start + t * 64 + lane;
    bool v0 = (tkn >= myLo) && (tkn < myHi) && ((tkn >> 6) != mw);
    unsigned nk = ~(unsigned)tkn;
#pragma unroll
    for (int j = 0; j < 3; ++j) {
      unsigned cc = v0 ? ordf(acc[j]) : 0u;
      unsigned long long key =
          cc ? (((unsigned long long)cc << 32) | nk) : 0ULL;
      if (key > lst[j][KT - 1]) {
        unsigned long long ins = key;
#pragma unroll
        for (int r = 0; r < KT; ++r) {
          unsigned long long cur = lst[j][r];
          unsigned long long mx = ins > cur ? ins : cur;
          unsigned long long mn = ins > cur ? cur : ins;
          lst[j][r] = mx;
          ins = mn;
        }
      }
    }
    // ---- rotate buffers: stage chunk t+1 to LDS, issue t+2 ----
    if (t + 1 < nt) {
      BAR();                 // all waves done reading kbuf[(t+1)&1]
      writeb((t + 1) & 1);   // reg -> LDS (implicit vmcnt wait on pre)
      if (t + 2 < nt) issue(t + 2);  // loads in flight over next compute
      BAR();                 // staged chunk visible (lgkm only)
    }
  }

  // ---- extraction merge across 64 lanes (3 queries interleaved) ----
  for (int k = 0; k < KT; ++k) {
    unsigned long long mx[3];
#pragma unroll
    for (int j = 0; j < 3; ++j) mx[j] = lst[j][0];
#pragma unroll
    for (int s_ = 1; s_ < 64; s_ <<= 1) {
#pragma unroll
      for (int j = 0; j < 3; ++j) {
        unsigned long long o = __shfl_xor(mx[j], s_, 64);
        if (o > mx[j]) mx[j] = o;
      }
    }
#pragma unroll
    for (int j = 0; j < 3; ++j) {
      if (mx[j] != 0ULL && lst[j][0] == mx[j]) {
#pragma unroll
        for (int r = 0; r < KT - 1; ++r) lst[j][r] = lst[j][r + 1];
        lst[j][KT - 1] = 0ULL;
      }
    }
    if (lane == 0) {
#pragma unroll
      for (int j = 0; j < 3; ++j) {
        int q = pr * 12 + w * 3 + j;
        topk2[((size_t)(q * NH + h) * 2 + sp) * KT + k] = mx[j];
      }
    }
  }
}

// ---------- 6. merge splits + softmax + gather V + Wo + scatter-add + avg ----------
__global__ __launch_bounds__(256) void finish_kernel(
    const unsigned long long* __restrict__ topk2, const float* __restrict__ V,
    const float4* __restrict__ WoP, const float* __restrict__ bo,
    const int* __restrict__ selected, float* __restrict__ out,
    float* __restrict__ out_avg) {
  int q0 = blockIdx.x * 16;
  int tid = threadIdx.x;
  __shared__ unsigned long long buf[64][2 * KT];  // 10 KB
  __shared__ float tvs[16][NH][KT];
  __shared__ int tis[16][NH][KT];
  __shared__ float wsm[16][NH * KT];
  __shared__ float att[16][256];
  // stage the 64 (q,h) pairs' split lists
  const unsigned long long* src = topk2 + (size_t)q0 * NH * 2 * KT;
  for (int i = tid; i < 64 * 2 * KT; i += 256) (&buf[0][0])[i] = src[i];
  __syncthreads();
  if (tid < 64) {
    int qq = tid >> 2, h = tid & 3;
    // two-pointer exact merge of the two sorted-desc lists + inline softmax
    int pa = 0, pb = 0;
    float e[KT];
    float m0 = 0.f, sum = 0.f;
#pragma unroll
    for (int k = 0; k < KT; ++k) {
      unsigned long long va = buf[tid][pa];
      unsigned long long vb = buf[tid][KT + pb];
      unsigned long long v;
      if (va >= vb) { v = va; ++pa; } else { v = vb; ++pb; }
      float scv;
      int t;
      if (v != 0ULL) {
        scv = unordf((unsigned)(v >> 32));
        t = (int)(~(unsigned)v);
      } else {
        scv = -1e30f;
        t = 0;
      }
      tvs[qq][h][k] = scv;
      tis[qq][h][k] = t;
      if (k == 0) m0 = scv;
      e[k] = expf(scv - m0);
      sum += e[k];
    }
    float inv = 1.f / sum;
#pragma unroll
    for (int k = 0; k < KT; ++k) wsm[qq][h * KT + k] = e[k] * inv;
  }
  __syncthreads();
  if (tid < 160) {
    int qq = tid / 10, k = tid % 10;
    out_avg[(size_t)(q0 + qq) * KT + k] =
        0.25f * (tvs[qq][0][k] + tvs[qq][1][k] + tvs[qq][2][k] + tvs[qq][3][k]);
  }
  int h = tid >> 6, d = tid & 63;
#pragma unroll 1
  for (int qq = 0; qq < 16; ++qq) {
    float a = 0.f;
#pragma unroll
    for (int k = 0; k < KT; ++k) {
      int t = tis[qq][h][k];
      a += wsm[qq][h * KT + k] * V[(size_t)t * 256 + h * 64 + d];
    }
    att[qq][tid] = a;
  }
  __syncthreads();
  float acc[16];
#pragma unroll
  for (int tt = 0; tt < 16; ++tt) acc[tt] = 0.f;
  for (int i4 = 0; i4 < 64; ++i4) {
    float4 wv = WoP[i4 * 256 + tid];  // coalesced panel load
#pragma unroll
    for (int tt = 0; tt < 16; ++tt) {
      float4 x = ((const float4*)att[tt])[i4];
      acc[tt] += x.x * wv.x + x.y * wv.y + x.z * wv.z + x.w * wv.w;
    }
  }
  float bj = bo[tid];
#pragma unroll 1
  for (int tt = 0; tt < 16; ++tt) {
    int s = selected[q0 + tt];
    out[(size_t)s * 256 + tid] += acc[tt] + bj;
  }
}

// ---------- launch ----------
extern "C" void kernel_launch(void* const* d_in, const int* in_sizes, int n_in,
                              void* d_out, int out_size, void* d_ws, size_t ws_size,
                              hipStream_t stream) {
  const float* X   = (const float*)d_in[0];
  const int*   mb  = (const int*)d_in[1];
  const int*   bidx= (const int*)d_in[2];
  const float* Wq  = (const float*)d_in[3];
  const float* bq  = (const float*)d_in[4];
  const float* Wk  = (const float*)d_in[5];
  const float* bk  = (const float*)d_in[6];
  const float* Wv  = (const float*)d_in[7];
  const float* bv  = (const float*)d_in[8];
  const float* Wi1 = (const float*)d_in[9];
  const float* bi1 = (const float*)d_in[10];
  const float* Wi2 = (const float*)d_in[11];
  const float* bi2 = (const float*)d_in[12];
  const float* Wo  = (const float*)d_in[13];
  const float* bo  = (const float*)d_in[14];

  float* out = (float*)d_out;
  float* out_avg = out + (size_t)T_TOK * D_HID;

  // K is staged in d_out's "updated" region (dead until final memcpy+scatter).
  float* Kmat = out;

  char* ws = (char*)d_ws;
  size_t off = 0;
  float* V = (float*)(ws + off);        off += (size_t)T_TOK * 256 * 4;   // 16.78 MB
  float* Q = (float*)(ws + off);        off += (size_t)NQ * 256 * 4;      // 1.57 MB
  float* imp = (float*)(ws + off);      off += (size_t)T_TOK * 4;
  int* selected = (int*)(ws + off);     off += (size_t)NQ * 4;
  int* lo = (int*)(ws + off);           off += 64;
  int* hi = (int*)(ws + off);           off += 64;
  unsigned long long* topk2 = (unsigned long long*)(ws + off);
  off += (size_t)NQ * NH * 2 * KT * 8;                                    // 0.98 MB
  float4* WkP = (float4*)(ws + off);    off += (size_t)64 * 256 * 16;     // 256 KB
  float4* WvP = (float4*)(ws + off);    off += (size_t)64 * 256 * 16;
  float4* WqP = (float4*)(ws + off);    off += (size_t)64 * 256 * 16;
  float4* WoP = (float4*)(ws + off);    off += (size_t)64 * 256 * 16;
  float4* Wi1P = (float4*)(ws + off);   off += (size_t)64 * 128 * 16;     // 128 KB
  (void)ws_size; (void)in_sizes; (void)n_in; (void)out_size;

  wpanel_kernel<<<256, 64, 0, stream>>>(Wk, Wv, Wq, Wo, Wi1, WkP, WvP, WqP,
                                        WoP, Wi1P);
  imp_kernel<<<T_TOK / 16, 128, 0, stream>>>(X, Wi1P, bi1, Wi2, bi2, imp);
  topsel_kernel<<<M_MSG + 1, 64, 0, stream>>>(imp, mb, bidx, selected, lo, hi);
  projkvq_kernel<<<T_TOK / 16 + NQ / 32, 256, 0, stream>>>(
      X, WkP, bk, WvP, bv, WqP, bq, selected, Kmat, V, Q);
  scores_kernel<<<M_MSG / 2 * NH * 2, 256, 0, stream>>>(Q, Kmat, lo, hi, bidx,
                                                        topk2);
  hipMemcpyAsync(out, X, (size_t)T_TOK * D_HID * sizeof(float),
                 hipMemcpyDeviceToDevice, stream);
  finish_kernel<<<NQ / 16, 256, 0, stream>>>(topk2, V, WoP, bo, selected, out,
                                             out_avg);
}

// Round 8
// 422.475 us; speedup vs baseline: 1.1482x; 1.1482x over previous
//
#include <hip/hip_runtime.h>
#include <math.h>

#define T_TOK 16384
#define M_MSG 256
#define L_TOK 64
#define KK 6
#define NQ (M_MSG * KK)   // 1536
#define D_HID 256
#define NH 4
#define HD 64
#define KT 10
#define NBATCH 8

// ---------- helpers ----------
__device__ __forceinline__ unsigned ordf(float f) {
  unsigned u = __float_as_uint(f);
  return (u & 0x80000000u) ? ~u : (u | 0x80000000u);
}
__device__ __forceinline__ float unordf(unsigned u) {
  return __uint_as_float((u & 0x80000000u) ? (u ^ 0x80000000u) : ~u);
}

// ---------- 0. weight k-panel transpose ----------
__global__ __launch_bounds__(64) void wpanel_kernel(
    const float* __restrict__ Wk, const float* __restrict__ Wv,
    const float* __restrict__ Wq, const float* __restrict__ Wo,
    const float* __restrict__ Wi1, float4* __restrict__ WkP,
    float4* __restrict__ WvP, float4* __restrict__ WqP,
    float4* __restrict__ WoP, float4* __restrict__ Wi1P) {
  int c = blockIdx.x;    // 0..255 (column)
  int k4 = threadIdx.x;  // 0..63 (dim group)
  WkP[k4 * 256 + c] = ((const float4*)(Wk + (size_t)c * 256))[k4];
  WvP[k4 * 256 + c] = ((const float4*)(Wv + (size_t)c * 256))[k4];
  WqP[k4 * 256 + c] = ((const float4*)(Wq + (size_t)c * 256))[k4];
  WoP[k4 * 256 + c] = ((const float4*)(Wo + (size_t)c * 256))[k4];
  if (c < 128) Wi1P[k4 * 128 + c] = ((const float4*)(Wi1 + (size_t)c * 256))[k4];
}

// ---------- 1. importance MLP ----------
__global__ __launch_bounds__(128) void imp_kernel(
    const float* __restrict__ X, const float4* __restrict__ Wi1P,
    const float* __restrict__ bi1, const float* __restrict__ Wi2,
    const float* __restrict__ bi2, float* __restrict__ imp) {
  __shared__ float xs[16][256];
  __shared__ float partial[2][16];
  int t0 = blockIdx.x * 16;
  int tid = threadIdx.x;  // 0..127, = hidden index j
  const float4* Xv = (const float4*)(X + (size_t)t0 * 256);
  float4* xsv = (float4*)&xs[0][0];
  for (int r = tid; r < 1024; r += 128) xsv[r] = Xv[r];
  __syncthreads();
  float acc[16];
#pragma unroll
  for (int tt = 0; tt < 16; ++tt) acc[tt] = 0.f;
  for (int i4 = 0; i4 < 64; ++i4) {
    float4 w = Wi1P[i4 * 128 + tid];  // coalesced panel load
#pragma unroll
    for (int tt = 0; tt < 16; ++tt) {
      float4 x = ((const float4*)xs[tt])[i4];
      acc[tt] += x.x * w.x + x.y * w.y + x.z * w.z + x.w * w.w;
    }
  }
  float b1 = bi1[tid], w2 = Wi2[tid];
  float p[16];
#pragma unroll
  for (int tt = 0; tt < 16; ++tt) {
    float hh = acc[tt] + b1;
    hh = hh > 0.f ? hh : 0.f;
    p[tt] = hh * w2;
  }
#pragma unroll
  for (int s = 1; s < 64; s <<= 1) {
#pragma unroll
    for (int tt = 0; tt < 16; ++tt) p[tt] += __shfl_xor(p[tt], s, 64);
  }
  int lane = tid & 63, w = tid >> 6;
  if (lane == 0) {
#pragma unroll
    for (int tt = 0; tt < 16; ++tt) partial[w][tt] = p[tt];
  }
  __syncthreads();
  if (tid < 16) imp[t0 + tid] = partial[0][tid] + partial[1][tid] + bi2[0];
}

// ---------- 2. per-message top-6 + (block M_MSG) batch ranges ----------
__global__ __launch_bounds__(64) void topsel_kernel(
    const float* __restrict__ imp, const int* __restrict__ mb,
    const int* __restrict__ bidx, int* __restrict__ selected,
    int* __restrict__ lo, int* __restrict__ hi) {
  int m = blockIdx.x;
  if (m == M_MSG) {  // fused ranges computation
    int g = threadIdx.x;
    if (g < NBATCH) {
      int l = 0;
      while (l < M_MSG && bidx[l] < g) ++l;
      int h = l;
      while (h < M_MSG && bidx[h] == g) ++h;
      lo[g] = l * L_TOK;
      hi[g] = h * L_TOK;
    }
    return;
  }
  int l = threadIdx.x;  // 0..63
  float myv = imp[m * 64 + l];
  int start = mb[2 * m];
  for (int k = 0; k < KK; ++k) {
    float rv = myv;
    int ri = l;
#pragma unroll
    for (int s = 1; s < 64; s <<= 1) {
      float ov = __shfl_xor(rv, s, 64);
      int oi = __shfl_xor(ri, s, 64);
      if (ov > rv || (ov == rv && oi < ri)) { rv = ov; ri = oi; }
    }
    if (l == 0) selected[m * KK + k] = start + ri;
    if (l == ri) myv = -INFINITY;
  }
}

// ---------- 4. fused K+V+Q projections (panel weights) ----------
__global__ __launch_bounds__(256) void projkvq_kernel(
    const float* __restrict__ X, const float4* __restrict__ WkP,
    const float* __restrict__ bk, const float4* __restrict__ WvP,
    const float* __restrict__ bv, const float4* __restrict__ WqP,
    const float* __restrict__ bq, const int* __restrict__ selected,
    float* __restrict__ Kout, float* __restrict__ Vout,
    float* __restrict__ Qout) {
  __shared__ float xs[32][260];  // +4 pad: transpose reads 2-way max
  int tid = threadIdx.x;
  if (blockIdx.x < T_TOK / 16) {
    // ---- KV path ----
    int r0 = blockIdx.x * 16;
    const float4* Xv = (const float4*)(X + (size_t)r0 * 256);
    for (int n = tid; n < 1024; n += 256) {
      int row = n >> 6, sl = n & 63;
      ((float4*)xs[row])[sl] = Xv[row * 64 + sl];
    }
    __syncthreads();
    float ak[16], av[16];
#pragma unroll
    for (int tt = 0; tt < 16; ++tt) { ak[tt] = 0.f; av[tt] = 0.f; }
    for (int i4 = 0; i4 < 64; ++i4) {
      float4 wk = WkP[i4 * 256 + tid];  // coalesced panel loads
      float4 wv = WvP[i4 * 256 + tid];
#pragma unroll
      for (int tt = 0; tt < 16; ++tt) {
        float4 x = ((const float4*)xs[tt])[i4];
        ak[tt] += x.x * wk.x + x.y * wk.y + x.z * wk.z + x.w * wk.w;
        av[tt] += x.x * wv.x + x.y * wv.y + x.z * wv.z + x.w * wv.w;
      }
    }
    float bkj = bk[tid], bvj = bv[tid];
#pragma unroll 1
    for (int tt = 0; tt < 16; ++tt)
      Vout[(size_t)(r0 + tt) * 256 + tid] = av[tt] + bvj;
    __syncthreads();  // all FMA reads of xs done
#pragma unroll
    for (int tt = 0; tt < 16; ++tt) xs[tt][tid] = ak[tt] + bkj;
    __syncthreads();
    float4* K4v = (float4*)Kout;
#pragma unroll
    for (int i = 0; i < 4; ++i) {
      int idx = i * 256 + tid;
      int hd4 = idx >> 4, r = idx & 15;
      float4 kv = *(const float4*)&xs[r][hd4 * 4];
      K4v[(size_t)hd4 * T_TOK + r0 + r] = kv;
    }
  } else {
    // ---- Q path (gathered rows, scaled) ----
    int r0 = (blockIdx.x - T_TOK / 16) * 32;
    for (int rr = 0; rr < 32; ++rr) {
      int r = r0 + rr;
      if (r < NQ) xs[rr][tid] = X[(size_t)selected[r] * 256 + tid];
    }
    __syncthreads();
    float acc[32];
#pragma unroll
    for (int tt = 0; tt < 32; ++tt) acc[tt] = 0.f;
    for (int i4 = 0; i4 < 64; ++i4) {
      float4 w = WqP[i4 * 256 + tid];
#pragma unroll
      for (int tt = 0; tt < 32; ++tt) {
        float4 x = ((const float4*)xs[tt])[i4];
        acc[tt] += x.x * w.x + x.y * w.y + x.z * w.z + x.w * w.w;
      }
    }
    float bj = bq[tid];
#pragma unroll 1
    for (int tt = 0; tt < 32; ++tt) {
      int r = r0 + tt;
      if (r < NQ) Qout[(size_t)r * 256 + tid] = (acc[tt] + bj) * 0.125f;
    }
  }
}

// ---------- 5. scores + per-split top-10 ----------
// block = (m, h, split): 2048 blocks, 192 threads = 3 waves.
// ZERO LDS in the kernel (r3/r5's 48 ds_read_b128 of Q per chunk saturated
// the per-CU LDS unit at ~12cyc each = the ~150us wall). Wave w owns
// queries {2w, 2w+1}, HOISTED INTO REGISTERS once (32 float4, statically
// indexed). K dim-major K4[h*16+d4][T]: lane L's load of (d4, t=base+L) is
// 64x16B contiguous -> registers via A/B double-buffer (loads for half n+1
// in flight over compute of half n). Per-lane u64 top-10 lists (r5 scheme,
// best measured); shfl extraction-merge epilogue. No barriers anywhere.
__global__ __launch_bounds__(192) void scores_kernel(
    const float* __restrict__ Q, const float* __restrict__ K4,
    const int* __restrict__ lo_, const int* __restrict__ hi_,
    const int* __restrict__ bidx, unsigned long long* __restrict__ topk2) {
  int bid = blockIdx.x;
  // XCD swizzle: contiguous 256-block slab per XCD (bidx sorted).
  int sw = (bid & 7) * (M_MSG * NH * 2 / 8) + (bid >> 3);
  int m = sw >> 3;
  int h = (sw >> 1) & 3;
  int sp = sw & 1;
  int tid = threadIdx.x, lane = tid & 63, w = tid / 64;  // w = 0..2
  int g = bidx[m];
  int lo = lo_[g], hi = hi_[g];
  int range = hi - lo;
  int n_all = (range + 63) >> 6;
  int n0 = (n_all + 1) >> 1;
  int nt = sp ? (n_all - n0) : n0;
  int start = lo + (sp ? n0 * 64 : 0);
  int end0 = lo + n0 * 64;
  int end = sp ? hi : (end0 < hi ? end0 : hi);

  const float4* Qv = (const float4*)Q;
  const float4* Kh = (const float4*)K4 + (size_t)h * 16 * T_TOK;

  // hoist this wave's 2 queries into registers (32 float4)
  const float4* Qg0 = Qv + (size_t)(m * KK + w * 2 + 0) * 64 + h * 16;
  const float4* Qg1 = Qv + (size_t)(m * KK + w * 2 + 1) * 64 + h * 16;
  float4 q0r[16], q1r[16];
#pragma unroll
  for (int d4 = 0; d4 < 16; ++d4) {
    q0r[d4] = Qg0[d4];
    q1r[d4] = Qg1[d4];
  }

  unsigned long long lst[2][KT];
#pragma unroll
  for (int j = 0; j < 2; ++j)
#pragma unroll
    for (int k = 0; k < KT; ++k) lst[j][k] = 0ULL;

  float4 A[8], B[8];
  float acc[2];

#define LOADH(BUF, KB, HALF)                                        \
  do {                                                              \
    int t_ = start + (KB)*64 + lane;                                \
    int tc_ = t_ < hi ? t_ : hi - 1;                                \
    _Pragma("unroll")                                               \
    for (int d_ = 0; d_ < 8; ++d_)                                  \
      BUF[d_] = Kh[(size_t)((HALF)*8 + d_) * T_TOK + tc_];          \
  } while (0)

#define COMPUTE(BUF, HALF)                                          \
  do {                                                              \
    _Pragma("unroll")                                               \
    for (int d_ = 0; d_ < 8; ++d_) {                                \
      float4 kv_ = BUF[d_];                                         \
      float4 qa_ = q0r[(HALF)*8 + d_];                              \
      float4 qb_ = q1r[(HALF)*8 + d_];                              \
      acc[0] += kv_.x * qa_.x + kv_.y * qa_.y + kv_.z * qa_.z +     \
                kv_.w * qa_.w;                                      \
      acc[1] += kv_.x * qb_.x + kv_.y * qb_.y + kv_.z * qb_.z +     \
                kv_.w * qb_.w;                                      \
    }                                                               \
  } while (0)

  if (nt > 0) LOADH(A, 0, 0);
#pragma unroll 1
  for (int kb = 0; kb < nt; ++kb) {
    LOADH(B, kb, 1);        // issue half-1 loads (in flight over compute A)
    acc[0] = 0.f; acc[1] = 0.f;
    COMPUTE(A, 0);
    if (kb + 1 < nt) LOADH(A, kb + 1, 0);  // next chunk half-0 in flight
    COMPUTE(B, 1);
    // ---- validity + per-lane register top-10 insert ----
    int t = start + kb * 64 + lane;
    bool v0 = (t < end) && ((t >> 6) != m);
    unsigned nk = ~(unsigned)t;
#pragma unroll
    for (int j = 0; j < 2; ++j) {
      unsigned cc = v0 ? ordf(acc[j]) : 0u;
      unsigned long long key =
          cc ? (((unsigned long long)cc << 32) | nk) : 0ULL;
      if (key > lst[j][KT - 1]) {
        unsigned long long ins = key;
#pragma unroll
        for (int r = 0; r < KT; ++r) {
          unsigned long long cur = lst[j][r];
          unsigned long long mx = ins > cur ? ins : cur;
          unsigned long long mn = ins > cur ? cur : ins;
          lst[j][r] = mx;
          ins = mn;
        }
      }
    }
  }
#undef LOADH
#undef COMPUTE

  // ---- extraction merge across 64 lanes (2 queries interleaved) ----
  for (int k = 0; k < KT; ++k) {
    unsigned long long mx[2];
#pragma unroll
    for (int j = 0; j < 2; ++j) mx[j] = lst[j][0];
#pragma unroll
    for (int s_ = 1; s_ < 64; s_ <<= 1) {
#pragma unroll
      for (int j = 0; j < 2; ++j) {
        unsigned long long o = __shfl_xor(mx[j], s_, 64);
        if (o > mx[j]) mx[j] = o;
      }
    }
#pragma unroll
    for (int j = 0; j < 2; ++j) {
      if (mx[j] != 0ULL && lst[j][0] == mx[j]) {
#pragma unroll
        for (int r = 0; r < KT - 1; ++r) lst[j][r] = lst[j][r + 1];
        lst[j][KT - 1] = 0ULL;
      }
    }
    if (lane == 0) {
#pragma unroll
      for (int j = 0; j < 2; ++j) {
        int q = m * KK + w * 2 + j;
        topk2[((size_t)(q * NH + h) * 2 + sp) * KT + k] = mx[j];
      }
    }
  }
}

// ---------- 6. merge splits + softmax + gather V + Wo + scatter-add + avg ----------
__global__ __launch_bounds__(256) void finish_kernel(
    const unsigned long long* __restrict__ topk2, const float* __restrict__ V,
    const float4* __restrict__ WoP, const float* __restrict__ bo,
    const int* __restrict__ selected, float* __restrict__ out,
    float* __restrict__ out_avg) {
  int q0 = blockIdx.x * 16;
  int tid = threadIdx.x;
  __shared__ unsigned long long buf[64][2 * KT];  // 10 KB
  __shared__ float tvs[16][NH][KT];
  __shared__ int tis[16][NH][KT];
  __shared__ float wsm[16][NH * KT];
  __shared__ float att[16][256];
  // stage the 64 (q,h) pairs' split lists
  const unsigned long long* src = topk2 + (size_t)q0 * NH * 2 * KT;
  for (int i = tid; i < 64 * 2 * KT; i += 256) (&buf[0][0])[i] = src[i];
  __syncthreads();
  if (tid < 64) {
    int qq = tid >> 2, h = tid & 3;
    // two-pointer exact merge of the two sorted-desc lists + inline softmax
    int pa = 0, pb = 0;
    float e[KT];
    float m0 = 0.f, sum = 0.f;
#pragma unroll
    for (int k = 0; k < KT; ++k) {
      unsigned long long va = buf[tid][pa];
      unsigned long long vb = buf[tid][KT + pb];
      unsigned long long v;
      if (va >= vb) { v = va; ++pa; } else { v = vb; ++pb; }
      float scv;
      int t;
      if (v != 0ULL) {
        scv = unordf((unsigned)(v >> 32));
        t = (int)(~(unsigned)v);
      } else {
        scv = -1e30f;
        t = 0;
      }
      tvs[qq][h][k] = scv;
      tis[qq][h][k] = t;
      if (k == 0) m0 = scv;
      e[k] = expf(scv - m0);
      sum += e[k];
    }
    float inv = 1.f / sum;
#pragma unroll
    for (int k = 0; k < KT; ++k) wsm[qq][h * KT + k] = e[k] * inv;
  }
  __syncthreads();
  if (tid < 160) {
    int qq = tid / 10, k = tid % 10;
    out_avg[(size_t)(q0 + qq) * KT + k] =
        0.25f * (tvs[qq][0][k] + tvs[qq][1][k] + tvs[qq][2][k] + tvs[qq][3][k]);
  }
  int h = tid >> 6, d = tid & 63;
#pragma unroll 1
  for (int qq = 0; qq < 16; ++qq) {
    float a = 0.f;
#pragma unroll
    for (int k = 0; k < KT; ++k) {
      int t = tis[qq][h][k];
      a += wsm[qq][h * KT + k] * V[(size_t)t * 256 + h * 64 + d];
    }
    att[qq][tid] = a;
  }
  __syncthreads();
  float acc[16];
#pragma unroll
  for (int tt = 0; tt < 16; ++tt) acc[tt] = 0.f;
  for (int i4 = 0; i4 < 64; ++i4) {
    float4 wv = WoP[i4 * 256 + tid];  // coalesced panel load
#pragma unroll
    for (int tt = 0; tt < 16; ++tt) {
      float4 x = ((const float4*)att[tt])[i4];
      acc[tt] += x.x * wv.x + x.y * wv.y + x.z * wv.z + x.w * wv.w;
    }
  }
  float bj = bo[tid];
#pragma unroll 1
  for (int tt = 0; tt < 16; ++tt) {
    int s = selected[q0 + tt];
    out[(size_t)s * 256 + tid] += acc[tt] + bj;
  }
}

// ---------- launch ----------
extern "C" void kernel_launch(void* const* d_in, const int* in_sizes, int n_in,
                              void* d_out, int out_size, void* d_ws, size_t ws_size,
                              hipStream_t stream) {
  const float* X   = (const float*)d_in[0];
  const int*   mb  = (const int*)d_in[1];
  const int*   bidx= (const int*)d_in[2];
  const float* Wq  = (const float*)d_in[3];
  const float* bq  = (const float*)d_in[4];
  const float* Wk  = (const float*)d_in[5];
  const float* bk  = (const float*)d_in[6];
  const float* Wv  = (const float*)d_in[7];
  const float* bv  = (const float*)d_in[8];
  const float* Wi1 = (const float*)d_in[9];
  const float* bi1 = (const float*)d_in[10];
  const float* Wi2 = (const float*)d_in[11];
  const float* bi2 = (const float*)d_in[12];
  const float* Wo  = (const float*)d_in[13];
  const float* bo  = (const float*)d_in[14];

  float* out = (float*)d_out;
  float* out_avg = out + (size_t)T_TOK * D_HID;

  // K is staged in d_out's "updated" region (dead until final memcpy+scatter).
  float* Kmat = out;

  char* ws = (char*)d_ws;
  size_t off = 0;
  float* V = (float*)(ws + off);        off += (size_t)T_TOK * 256 * 4;   // 16.78 MB
  float* Q = (float*)(ws + off);        off += (size_t)NQ * 256 * 4;      // 1.57 MB
  float* imp = (float*)(ws + off);      off += (size_t)T_TOK * 4;
  int* selected = (int*)(ws + off);     off += (size_t)NQ * 4;
  int* lo = (int*)(ws + off);           off += 64;
  int* hi = (int*)(ws + off);           off += 64;
  unsigned long long* topk2 = (unsigned long long*)(ws + off);
  off += (size_t)NQ * NH * 2 * KT * 8;                                    // 0.98 MB
  float4* WkP = (float4*)(ws + off);    off += (size_t)64 * 256 * 16;     // 256 KB
  float4* WvP = (float4*)(ws + off);    off += (size_t)64 * 256 * 16;
  float4* WqP = (float4*)(ws + off);    off += (size_t)64 * 256 * 16;
  float4* WoP = (float4*)(ws + off);    off += (size_t)64 * 256 * 16;
  float4* Wi1P = (float4*)(ws + off);   off += (size_t)64 * 128 * 16;     // 128 KB
  (void)ws_size; (void)in_sizes; (void)n_in; (void)out_size;

  wpanel_kernel<<<256, 64, 0, stream>>>(Wk, Wv, Wq, Wo, Wi1, WkP, WvP, WqP,
                                        WoP, Wi1P);
  imp_kernel<<<T_TOK / 16, 128, 0, stream>>>(X, Wi1P, bi1, Wi2, bi2, imp);
  topsel_kernel<<<M_MSG + 1, 64, 0, stream>>>(imp, mb, bidx, selected, lo, hi);
  projkvq_kernel<<<T_TOK / 16 + NQ / 32, 256, 0, stream>>>(
      X, WkP, bk, WvP, bv, WqP, bq, selected, Kmat, V, Q);
  scores_kernel<<<M_MSG * NH * 2, 192, 0, stream>>>(Q, Kmat, lo, hi, bidx,
                                                    topk2);
  hipMemcpyAsync(out, X, (size_t)T_TOK * D_HID * sizeof(float),
                 hipMemcpyDeviceToDevice, stream);
  finish_kernel<<<NQ / 16, 256, 0, stream>>>(topk2, V, WoP, bo, selected, out,
                                             out_avg);
}

// Round 10
// 337.849 us; speedup vs baseline: 1.4358x; 1.2505x over previous
//
#include <hip/hip_runtime.h>
#include <math.h>

#define T_TOK 16384
#define M_MSG 256
#define L_TOK 64
#define KK 6
#define NQ (M_MSG * KK)   // 1536
#define D_HID 256
#define NH 4
#define HD 64
#define KT 10
#define NBATCH 8

// ---------- helpers ----------
__device__ __forceinline__ unsigned ordf(float f) {
  unsigned u = __float_as_uint(f);
  return (u & 0x80000000u) ? ~u : (u | 0x80000000u);
}
__device__ __forceinline__ float unordf(unsigned u) {
  return __uint_as_float((u & 0x80000000u) ? (u ^ 0x80000000u) : ~u);
}

// ---------- 0. weight k-panel transpose ----------
__global__ __launch_bounds__(64) void wpanel_kernel(
    const float* __restrict__ Wk, const float* __restrict__ Wv,
    const float* __restrict__ Wq, const float* __restrict__ Wo,
    const float* __restrict__ Wi1, float4* __restrict__ WkP,
    float4* __restrict__ WvP, float4* __restrict__ WqP,
    float4* __restrict__ WoP, float4* __restrict__ Wi1P) {
  int c = blockIdx.x;    // 0..255 (column)
  int k4 = threadIdx.x;  // 0..63 (dim group)
  WkP[k4 * 256 + c] = ((const float4*)(Wk + (size_t)c * 256))[k4];
  WvP[k4 * 256 + c] = ((const float4*)(Wv + (size_t)c * 256))[k4];
  WqP[k4 * 256 + c] = ((const float4*)(Wq + (size_t)c * 256))[k4];
  WoP[k4 * 256 + c] = ((const float4*)(Wo + (size_t)c * 256))[k4];
  if (c < 128) Wi1P[k4 * 128 + c] = ((const float4*)(Wi1 + (size_t)c * 256))[k4];
}

// ---------- 1. fused KV-projection + importance MLP (independent work,
// one dispatch so they run CONCURRENTLY) ----------
// blocks [0,1024): K (dim-major K4[h*16+d4][T] via LDS transpose) + V
// (row-major), 16 rows each. blocks [1024,1536): imp for 32 tokens each.
__global__ __launch_bounds__(256) void kvimp_kernel(
    const float* __restrict__ X, const float4* __restrict__ WkP,
    const float* __restrict__ bk, const float4* __restrict__ WvP,
    const float* __restrict__ bv, const float4* __restrict__ Wi1P,
    const float* __restrict__ bi1, const float* __restrict__ Wi2,
    const float* __restrict__ bi2, float* __restrict__ Kout,
    float* __restrict__ Vout, float* __restrict__ imp) {
  __shared__ float xs[32][260];  // +4 pad: KV transpose reads 2-way max
  __shared__ float partial[4][16];
  int tid = threadIdx.x;
  if (blockIdx.x < 1024) {
    // ---- KV path (16 rows) ----
    int r0 = blockIdx.x * 16;
    const float4* Xv = (const float4*)(X + (size_t)r0 * 256);
    for (int n = tid; n < 1024; n += 256) {
      int row = n >> 6, sl = n & 63;
      ((float4*)xs[row])[sl] = Xv[row * 64 + sl];
    }
    __syncthreads();
    float ak[16], av[16];
#pragma unroll
    for (int tt = 0; tt < 16; ++tt) { ak[tt] = 0.f; av[tt] = 0.f; }
    for (int i4 = 0; i4 < 64; ++i4) {
      float4 wk = WkP[i4 * 256 + tid];  // coalesced panel loads
      float4 wv = WvP[i4 * 256 + tid];
#pragma unroll
      for (int tt = 0; tt < 16; ++tt) {
        float4 x = ((const float4*)xs[tt])[i4];
        ak[tt] += x.x * wk.x + x.y * wk.y + x.z * wk.z + x.w * wk.w;
        av[tt] += x.x * wv.x + x.y * wv.y + x.z * wv.z + x.w * wv.w;
      }
    }
    float bkj = bk[tid], bvj = bv[tid];
#pragma unroll 1
    for (int tt = 0; tt < 16; ++tt)
      Vout[(size_t)(r0 + tt) * 256 + tid] = av[tt] + bvj;
    __syncthreads();  // all FMA reads of xs done
#pragma unroll
    for (int tt = 0; tt < 16; ++tt) xs[tt][tid] = ak[tt] + bkj;
    __syncthreads();
    float4* K4v = (float4*)Kout;
#pragma unroll
    for (int i = 0; i < 4; ++i) {
      int idx = i * 256 + tid;
      int hd4 = idx >> 4, r = idx & 15;
      float4 kv = *(const float4*)&xs[r][hd4 * 4];
      K4v[(size_t)hd4 * T_TOK + r0 + r] = kv;
    }
  } else {
    // ---- imp path (32 tokens; grp g = tid>>7 owns tokens g*16..+15) ----
    int t0 = (blockIdx.x - 1024) * 32;
    const float4* Xv = (const float4*)(X + (size_t)t0 * 256);
    for (int n = tid; n < 2048; n += 256) {
      int row = n >> 6, sl = n & 63;
      ((float4*)xs[row])[sl] = Xv[row * 64 + sl];
    }
    __syncthreads();
    int j = tid & 127, grp = tid >> 7;
    float acc[16];
#pragma unroll
    for (int tt = 0; tt < 16; ++tt) acc[tt] = 0.f;
    for (int i4 = 0; i4 < 64; ++i4) {
      float4 w = Wi1P[i4 * 128 + j];
#pragma unroll
      for (int tt = 0; tt < 16; ++tt) {
        float4 x = ((const float4*)xs[grp * 16 + tt])[i4];
        acc[tt] += x.x * w.x + x.y * w.y + x.z * w.z + x.w * w.w;
      }
    }
    float b1 = bi1[j], w2 = Wi2[j];
    float p[16];
#pragma unroll
    for (int tt = 0; tt < 16; ++tt) {
      float hh = acc[tt] + b1;
      hh = hh > 0.f ? hh : 0.f;
      p[tt] = hh * w2;
    }
#pragma unroll
    for (int s = 1; s < 64; s <<= 1) {
#pragma unroll
      for (int tt = 0; tt < 16; ++tt) p[tt] += __shfl_xor(p[tt], s, 64);
    }
    int lane = tid & 63, wv_ = tid >> 6;
    if (lane == 0) {
#pragma unroll
      for (int tt = 0; tt < 16; ++tt) partial[wv_][tt] = p[tt];
    }
    __syncthreads();
    if (tid < 32) {
      int g = tid >> 4, tt = tid & 15;
      imp[t0 + g * 16 + tt] =
          partial[2 * g][tt] + partial[2 * g + 1][tt] + bi2[0];
    }
  }
}

// ---------- 2. top-6 select + Q projection (fused) + (block M_MSG) ranges ----------
__global__ __launch_bounds__(256) void topselq_kernel(
    const float* __restrict__ imp, const int* __restrict__ mb,
    const int* __restrict__ bidx, const float* __restrict__ X,
    const float4* __restrict__ WqP, const float* __restrict__ bq,
    int* __restrict__ selected, int* __restrict__ lo, int* __restrict__ hi,
    float* __restrict__ Qout) {
  int m = blockIdx.x;
  int tid = threadIdx.x;
  if (m == M_MSG) {  // fused ranges computation
    int g = tid;
    if (g < NBATCH) {
      int l = 0;
      while (l < M_MSG && bidx[l] < g) ++l;
      int h = l;
      while (h < M_MSG && bidx[h] == g) ++h;
      lo[g] = l * L_TOK;
      hi[g] = h * L_TOK;
    }
    return;
  }
  __shared__ int sel[KK];
  __shared__ float4 xs6[KK][64];  // 6 selected rows x 256 floats (full row!)
  if (tid < 64) {  // wave 0: top-6 selection
    int l = tid;
    float myv = imp[m * 64 + l];
    int start = mb[2 * m];
    for (int k = 0; k < KK; ++k) {
      float rv = myv;
      int ri = l;
#pragma unroll
      for (int s = 1; s < 64; s <<= 1) {
        float ov = __shfl_xor(rv, s, 64);
        int oi = __shfl_xor(ri, s, 64);
        if (ov > rv || (ov == rv && oi < ri)) { rv = ov; ri = oi; }
      }
      if (l == 0) {
        selected[m * KK + k] = start + ri;
        sel[k] = start + ri;
      }
      if (l == ri) myv = -INFINITY;
    }
  }
  __syncthreads();
  for (int i = tid; i < KK * 64; i += 256) {  // stage full selected rows
    int r = i >> 6, d4 = i & 63;
    xs6[r][d4] = ((const float4*)X)[(size_t)sel[r] * 64 + d4];
  }
  __syncthreads();
  float acc[KK];
#pragma unroll
  for (int r = 0; r < KK; ++r) acc[r] = 0.f;
  for (int i4 = 0; i4 < 64; ++i4) {
    float4 w = WqP[i4 * 256 + tid];
#pragma unroll
    for (int r = 0; r < KK; ++r) {
      float4 x = xs6[r][i4];
      acc[r] += x.x * w.x + x.y * w.y + x.z * w.z + x.w * w.w;
    }
  }
  float bj = bq[tid];
#pragma unroll
  for (int r = 0; r < KK; ++r)
    Qout[(size_t)(m * KK + r) * 256 + tid] = (acc[r] + bj) * 0.125f;
}

// ---------- 5. scores + per-split top-10 ----------
// block = (message-PAIR, h, split): 1024 blocks, 256 threads = 4 waves.
// Messages of a pair share the same batch key range (bidx sorted), so the
// 4 waves stream the SAME K lines concurrently: L1 hits + MSHR merge make
// each unique L2 line serve 12 queries instead of 6 (the r5 wall was
// unique-miss concurrency). Per-wave dataflow is r5 VERBATIM: dim-major K,
// A/B register double-buffer, 3 queries/wave from LDS qs4, per-lane u64
// top-10 lists, shfl extraction-merge. Waves self-lockstep via L1
// (leader misses -> slows; laggard hits -> catches up). Boundary pairs
// (different batches) handled by per-wave [myLo,myHi) masks over the
// contiguous union range.
__global__ __launch_bounds__(256) void scores_kernel(
    const float* __restrict__ Q, const float* __restrict__ K4,
    const int* __restrict__ lo_, const int* __restrict__ hi_,
    const int* __restrict__ bidx, unsigned long long* __restrict__ topk2) {
  int bid = blockIdx.x;
  // XCD swizzle: 1024 blocks -> contiguous 128-block slab per XCD.
  int sw = (bid & 7) * 128 + (bid >> 3);
  int pr = sw >> 3;        // message pair 0..127
  int h = (sw >> 1) & 3;
  int sp = sw & 1;
  int tid = threadIdx.x, lane = tid & 63, w = tid >> 6;  // w = 0..3
  int m0 = pr * 2;
  int mw = m0 + (w >> 1);            // this wave's message
  int gw = bidx[mw];
  int myLo = lo_[gw], myHi = hi_[gw];
  int loU = lo_[bidx[m0]];
  int hiU = hi_[bidx[m0 + 1]];
  int range = hiU - loU;
  int n_all = (range + 63) >> 6;
  int n0 = (n_all + 1) >> 1;
  int nt = sp ? (n_all - n0) : n0;
  int start = loU + (sp ? n0 * 64 : 0);
  int end0 = loU + n0 * 64;
  int end = sp ? hiU : (end0 < hiU ? end0 : hiU);

  __shared__ float4 qs4[12][16];  // 12 queries x 64 dims (3 KB)
  const float4* Qv = (const float4*)Q;
  if (tid < 192) {
    int qq = tid >> 4, d4 = tid & 15;
    qs4[qq][d4] = Qv[(size_t)(pr * 12 + qq) * 64 + h * 16 + d4];
  }
  __syncthreads();

  unsigned long long lst[3][KT];
#pragma unroll
  for (int j = 0; j < 3; ++j)
#pragma unroll
    for (int k = 0; k < KT; ++k) lst[j][k] = 0ULL;

  const float4* Kh = (const float4*)K4 + (size_t)h * 16 * T_TOK;

  float4 A[8], B[8];
  float acc[3];

#define LOADH(BUF, KB, HALF)                                        \
  do {                                                              \
    int t_ = start + (KB)*64 + lane;                                \
    int tc_ = t_ < hiU ? t_ : hiU - 1;                              \
    _Pragma("unroll")                                               \
    for (int d_ = 0; d_ < 8; ++d_)                                  \
      BUF[d_] = Kh[(size_t)((HALF)*8 + d_) * T_TOK + tc_];          \
  } while (0)

#define COMPUTE(BUF, HALF)                                          \
  do {                                                              \
    _Pragma("unroll")                                               \
    for (int d_ = 0; d_ < 8; ++d_) {                                \
      _Pragma("unroll")                                             \
      for (int j_ = 0; j_ < 3; ++j_) {                              \
        float4 q_ = qs4[w * 3 + j_][(HALF)*8 + d_];                 \
        acc[j_] += BUF[d_].x * q_.x + BUF[d_].y * q_.y +            \
                   BUF[d_].z * q_.z + BUF[d_].w * q_.w;             \
      }                                                             \
    }                                                               \
  } while (0)

  if (nt > 0) LOADH(A, 0, 0);
#pragma unroll 1
  for (int kb = 0; kb < nt; ++kb) {
    LOADH(B, kb, 1);        // issue half-1 loads (in flight over compute A)
    acc[0] = 0.f; acc[1] = 0.f; acc[2] = 0.f;
    COMPUTE(A, 0);
    if (kb + 1 < nt) LOADH(A, kb + 1, 0);  // next chunk half-0 in flight
    COMPUTE(B, 1);
    // ---- validity + per-lane register top-10 insert (r5 scheme) ----
    int t = start + kb * 64 + lane;
    bool v0 = (t < end) && (t >= myLo) && (t < myHi) && ((t >> 6) != mw);
    unsigned nk = ~(unsigned)t;
#pragma unroll
    for (int j = 0; j < 3; ++j) {
      unsigned cc = v0 ? ordf(acc[j]) : 0u;
      unsigned long long key =
          cc ? (((unsigned long long)cc << 32) | nk) : 0ULL;
      if (key > lst[j][KT - 1]) {
        unsigned long long ins = key;
#pragma unroll
        for (int r = 0; r < KT; ++r) {
          unsigned long long cur = lst[j][r];
          unsigned long long mx = ins > cur ? ins : cur;
          unsigned long long mn = ins > cur ? cur : ins;
          lst[j][r] = mx;
          ins = mn;
        }
      }
    }
  }
#undef LOADH
#undef COMPUTE

  // ---- extraction merge across 64 lanes (3 queries interleaved) ----
  for (int k = 0; k < KT; ++k) {
    unsigned long long mx[3];
#pragma unroll
    for (int j = 0; j < 3; ++j) mx[j] = lst[j][0];
#pragma unroll
    for (int s_ = 1; s_ < 64; s_ <<= 1) {
#pragma unroll
      for (int j = 0; j < 3; ++j) {
        unsigned long long o = __shfl_xor(mx[j], s_, 64);
        if (o > mx[j]) mx[j] = o;
      }
    }
#pragma unroll
    for (int j = 0; j < 3; ++j) {
      if (mx[j] != 0ULL && lst[j][0] == mx[j]) {
#pragma unroll
        for (int r = 0; r < KT - 1; ++r) lst[j][r] = lst[j][r + 1];
        lst[j][KT - 1] = 0ULL;
      }
    }
    if (lane == 0) {
#pragma unroll
      for (int j = 0; j < 3; ++j) {
        int q = pr * 12 + w * 3 + j;
        topk2[((size_t)(q * NH + h) * 2 + sp) * KT + k] = mx[j];
      }
    }
  }
}

// ---------- 6. merge splits + softmax + gather V + Wo + scatter-add + avg ----------
__global__ __launch_bounds__(256) void finish_kernel(
    const unsigned long long* __restrict__ topk2, const float* __restrict__ V,
    const float4* __restrict__ WoP, const float* __restrict__ bo,
    const int* __restrict__ selected, float* __restrict__ out,
    float* __restrict__ out_avg) {
  int q0 = blockIdx.x * 16;
  int tid = threadIdx.x;
  __shared__ unsigned long long buf[64][2 * KT];  // 10 KB
  __shared__ float tvs[16][NH][KT];
  __shared__ int tis[16][NH][KT];
  __shared__ float wsm[16][NH * KT];
  __shared__ float att[16][256];
  // stage the 64 (q,h) pairs' split lists
  const unsigned long long* src = topk2 + (size_t)q0 * NH * 2 * KT;
  for (int i = tid; i < 64 * 2 * KT; i += 256) (&buf[0][0])[i] = src[i];
  __syncthreads();
  if (tid < 64) {
    int qq = tid >> 2, h = tid & 3;
    // two-pointer exact merge of the two sorted-desc lists + inline softmax
    int pa = 0, pb = 0;
    float e[KT];
    float m0 = 0.f, sum = 0.f;
#pragma unroll
    for (int k = 0; k < KT; ++k) {
      unsigned long long va = buf[tid][pa];
      unsigned long long vb = buf[tid][KT + pb];
      unsigned long long v;
      if (va >= vb) { v = va; ++pa; } else { v = vb; ++pb; }
      float scv;
      int t;
      if (v != 0ULL) {
        scv = unordf((unsigned)(v >> 32));
        t = (int)(~(unsigned)v);
      } else {
        scv = -1e30f;
        t = 0;
      }
      tvs[qq][h][k] = scv;
      tis[qq][h][k] = t;
      if (k == 0) m0 = scv;
      e[k] = expf(scv - m0);
      sum += e[k];
    }
    float inv = 1.f / sum;
#pragma unroll
    for (int k = 0; k < KT; ++k) wsm[qq][h * KT + k] = e[k] * inv;
  }
  __syncthreads();
  if (tid < 160) {
    int qq = tid / 10, k = tid % 10;
    out_avg[(size_t)(q0 + qq) * KT + k] =
        0.25f * (tvs[qq][0][k] + tvs[qq][1][k] + tvs[qq][2][k] + tvs[qq][3][k]);
  }
  int h = tid >> 6, d = tid & 63;
#pragma unroll 1
  for (int qq = 0; qq < 16; ++qq) {
    float a = 0.f;
#pragma unroll
    for (int k = 0; k < KT; ++k) {
      int t = tis[qq][h][k];
      a += wsm[qq][h * KT + k] * V[(size_t)t * 256 + h * 64 + d];
    }
    att[qq][tid] = a;
  }
  __syncthreads();
  float acc[16];
#pragma unroll
  for (int tt = 0; tt < 16; ++tt) acc[tt] = 0.f;
  for (int i4 = 0; i4 < 64; ++i4) {
    float4 wv = WoP[i4 * 256 + tid];  // coalesced panel load
#pragma unroll
    for (int tt = 0; tt < 16; ++tt) {
      float4 x = ((const float4*)att[tt])[i4];
      acc[tt] += x.x * wv.x + x.y * wv.y + x.z * wv.z + x.w * wv.w;
    }
  }
  float bj = bo[tid];
#pragma unroll 1
  for (int tt = 0; tt < 16; ++tt) {
    int s = selected[q0 + tt];
    out[(size_t)s * 256 + tid] += acc[tt] + bj;
  }
}

// ---------- launch ----------
extern "C" void kernel_launch(void* const* d_in, const int* in_sizes, int n_in,
                              void* d_out, int out_size, void* d_ws, size_t ws_size,
                              hipStream_t stream) {
  const float* X   = (const float*)d_in[0];
  const int*   mb  = (const int*)d_in[1];
  const int*   bidx= (const int*)d_in[2];
  const float* Wq  = (const float*)d_in[3];
  const float* bq  = (const float*)d_in[4];
  const float* Wk  = (const float*)d_in[5];
  const float* bk  = (const float*)d_in[6];
  const float* Wv  = (const float*)d_in[7];
  const float* bv  = (const float*)d_in[8];
  const float* Wi1 = (const float*)d_in[9];
  const float* bi1 = (const float*)d_in[10];
  const float* Wi2 = (const float*)d_in[11];
  const float* bi2 = (const float*)d_in[12];
  const float* Wo  = (const float*)d_in[13];
  const float* bo  = (const float*)d_in[14];

  float* out = (float*)d_out;
  float* out_avg = out + (size_t)T_TOK * D_HID;

  // K is staged in d_out's "updated" region (dead until final memcpy+scatter).
  float* Kmat = out;

  char* ws = (char*)d_ws;
  size_t off = 0;
  float* V = (float*)(ws + off);        off += (size_t)T_TOK * 256 * 4;   // 16.78 MB
  float* Q = (float*)(ws + off);        off += (size_t)NQ * 256 * 4;      // 1.57 MB
  float* imp = (float*)(ws + off);      off += (size_t)T_TOK * 4;
  int* selected = (int*)(ws + off);     off += (size_t)NQ * 4;
  int* lo = (int*)(ws + off);           off += 64;
  int* hi = (int*)(ws + off);           off += 64;
  unsigned long long* topk2 = (unsigned long long*)(ws + off);
  off += (size_t)NQ * NH * 2 * KT * 8;                                    // 0.98 MB
  float4* WkP = (float4*)(ws + off);    off += (size_t)64 * 256 * 16;     // 256 KB
  float4* WvP = (float4*)(ws + off);    off += (size_t)64 * 256 * 16;
  float4* WqP = (float4*)(ws + off);    off += (size_t)64 * 256 * 16;
  float4* WoP = (float4*)(ws + off);    off += (size_t)64 * 256 * 16;
  float4* Wi1P = (float4*)(ws + off);   off += (size_t)64 * 128 * 16;     // 128 KB
  (void)ws_size; (void)in_sizes; (void)n_in; (void)out_size;

  wpanel_kernel<<<256, 64, 0, stream>>>(Wk, Wv, Wq, Wo, Wi1, WkP, WvP, WqP,
                                        WoP, Wi1P);
  kvimp_kernel<<<1536, 256, 0, stream>>>(X, WkP, bk, WvP, bv, Wi1P, bi1, Wi2,
                                         bi2, Kmat, V, imp);
  topselq_kernel<<<M_MSG + 1, 256, 0, stream>>>(imp, mb, bidx, X, WqP, bq,
                                                selected, lo, hi, Q);
  scores_kernel<<<1024, 256, 0, stream>>>(Q, Kmat, lo, hi, bidx, topk2);
  hipMemcpyAsync(out, X, (size_t)T_TOK * D_HID * sizeof(float),
                 hipMemcpyDeviceToDevice, stream);
  finish_kernel<<<NQ / 16, 256, 0, stream>>>(topk2, V, WoP, bo, selected, out,
                                             out_avg);
}